// Round 1
// baseline (420.442 us; speedup 1.0000x reference)
//
#include <hip/hip_runtime.h>
#include <math.h>

#define N_RNA 4096
#define N_ATAC 8192
#define IN_C 256
#define HID 128
#define NH 2
#define TOPK 10
#define CAP 32
#define NCHUNK 8
#define TAU_EPS 0.12f
#define NEG_INF -3.402823466e38f

typedef __attribute__((ext_vector_type(8))) short bf16x8;
typedef __attribute__((ext_vector_type(4))) float f32x4;

static __device__ __forceinline__ f32x4 mfma16(bf16x8 a, bf16x8 b, f32x4 c) {
    return __builtin_amdgcn_mfma_f32_16x16x32_bf16(a, b, c, 0, 0, 0);
}

static __device__ __forceinline__ unsigned short f2bf(float f) {
    unsigned int u = __float_as_uint(f);
    unsigned int r = (u + 0x7fffu + ((u >> 16) & 1u)) >> 16;   // RNE
    return (unsigned short)r;
}
static __device__ __forceinline__ float bf2f(unsigned short h) {
    return __uint_as_float(((unsigned int)h) << 16);
}

// ---------------------------------------------------------------- K0: prep_all (block-ranged)
// [0,768): projections (32-row tiles).  [768,1792): mask->bits2 (float2, 2a/thr).
// [1792,2048): zero atac_agg.  [2048,2434): fuse weights.
__global__ __launch_bounds__(256) void prep_all(
    const float* __restrict__ mask, unsigned int* __restrict__ bits2,
    float* __restrict__ atac_agg,
    const float* __restrict__ Wor, const float* __restrict__ bor,
    const float* __restrict__ Woa, const float* __restrict__ boa,
    const float* __restrict__ Wsr, const float* __restrict__ bsr,
    const float* __restrict__ Wsa, const float* __restrict__ bsa,
    const float* __restrict__ Wdr, const float* __restrict__ bdr,
    const float* __restrict__ Wda, const float* __restrict__ bda,
    float* __restrict__ Wr1, float* __restrict__ Wr2, float* __restrict__ br,
    float* __restrict__ Wa1, float* __restrict__ Wa2, float* __restrict__ ba,
    const float* __restrict__ x_rna, const float* __restrict__ x_atac,
    const float* __restrict__ Wq, const float* __restrict__ bq,
    const float* __restrict__ Wk, const float* __restrict__ bk,
    const float* __restrict__ Wvr, const float* __restrict__ bvr,
    const float* __restrict__ Wva, const float* __restrict__ bva,
    unsigned short* __restrict__ qhi, unsigned short* __restrict__ qlo,
    unsigned short* __restrict__ khf_hi, unsigned short* __restrict__ khf_lo,
    float* __restrict__ v_r, float* __restrict__ v_a) {
    __shared__ __align__(16) float x_s[32][33];
    __shared__ __align__(16) float w_s[32][128];
    int bx = blockIdx.x;
    int tid = threadIdx.x;

    if (bx >= 768 && bx < 1792) {                 // ---- mask -> bits2, float2 (2 a/thread)
        int e = bx - 768;
        int rt = e >> 4, ac = e & 15;
        int a0 = ac * 512 + tid * 2;
        int r0 = rt * 64;
        unsigned int w0[2] = {0, 0}, w1[2] = {0, 0};
#pragma unroll 8
        for (int rr = 0; rr < 32; ++rr) {
            float2 m0 = *(const float2*)&mask[(size_t)(r0 + rr) * N_ATAC + a0];
            float2 m1 = *(const float2*)&mask[(size_t)(r0 + 32 + rr) * N_ATAC + a0];
            w0[0] |= ((m0.x > 0.5f) ? 1u : 0u) << rr;
            w0[1] |= ((m0.y > 0.5f) ? 1u : 0u) << rr;
            w1[0] |= ((m1.x > 0.5f) ? 1u : 0u) << rr;
            w1[1] |= ((m1.y > 0.5f) ? 1u : 0u) << rr;
        }
        uint4 o = make_uint4(w0[0], w1[0], w0[1], w1[1]);
        *(uint4*)&bits2[((size_t)rt * N_ATAC + a0) * 2] = o;
        return;
    }
    if (bx >= 1792 && bx < 2048) {                // ---- zero atac_agg (64 B/thread)
        size_t i = ((size_t)(bx - 1792) * 256 + tid) * 16;
        float4 z = make_float4(0.f, 0.f, 0.f, 0.f);
        *(float4*)&atac_agg[i] = z;
        *(float4*)&atac_agg[i + 4] = z;
        *(float4*)&atac_agg[i + 8] = z;
        *(float4*)&atac_agg[i + 12] = z;
        return;
    }
    if (bx >= 2048) {                             // ---- fuse weights
        int f = (bx - 2048) * 256 + tid;
        if (f < 16384) {
            int i = f >> 7, j = f & 127; float s = 0.f;
            for (int t = 0; t < 128; ++t) s += Wor[i * 128 + t] * Wdr[t * 128 + j];
            Wr1[f] = s;
        } else if (f < 49152) {
            int e = f - 16384; int i = e >> 7, j = e & 127; float s = 0.f;
            for (int t = 0; t < 128; ++t) s += Wsr[i * 128 + t] * Wdr[(128 + t) * 128 + j];
            Wr2[e] = s;
        } else if (f < 65536) {
            int e = f - 49152; int i = e >> 7, j = e & 127; float s = 0.f;
            for (int t = 0; t < 128; ++t) s += Woa[i * 128 + t] * Wda[t * 128 + j];
            Wa1[e] = s;
        } else if (f < 98304) {
            int e = f - 65536; int i = e >> 7, j = e & 127; float s = 0.f;
            for (int t = 0; t < 128; ++t) s += Wsa[i * 128 + t] * Wda[(128 + t) * 128 + j];
            Wa2[e] = s;
        } else if (f < 98432) {
            int j = f - 98304; float s = bdr[j];
            for (int t = 0; t < 128; ++t) s += bor[t] * Wdr[t * 128 + j] + bsr[t] * Wdr[(128 + t) * 128 + j];
            br[j] = s;
        } else if (f < 98560) {
            int j = f - 98432; float s = bda[j];
            for (int t = 0; t < 128; ++t) s += boa[t] * Wda[t * 128 + j] + bsa[t] * Wda[(128 + t) * 128 + j];
            ba[j] = s;
        }
        return;
    }

    // ---- projections (blocks [0,768)), 32-row tiles
    int e = bx;
    int cfg, rblk;
    if (e < 128)      { cfg = 0; rblk = e; }
    else if (e < 256) { cfg = 1; rblk = e - 128; }
    else if (e < 512) { cfg = 2; rblk = e - 256; }
    else              { cfg = 3; rblk = e - 512; }
    const float *X, *W, *B;
    if (cfg == 0)      { X = x_rna;  W = Wq;  B = bq;  }
    else if (cfg == 1) { X = x_rna;  W = Wvr; B = bvr; }
    else if (cfg == 2) { X = x_atac; W = Wk;  B = bk;  }
    else               { X = x_atac; W = Wva; B = bva; }
    int r0 = rblk * 32;
    int rg = tid >> 4, cg = tid & 15;

    float acc[2][8];
#pragma unroll
    for (int i = 0; i < 2; ++i)
#pragma unroll
        for (int j = 0; j < 8; ++j) acc[i][j] = 0.f;

    for (int k0 = 0; k0 < IN_C; k0 += 32) {
        __syncthreads();
        {   // stage X 32x32
            int rr = tid >> 3, kq = tid & 7;
            float4 v = *(const float4*)&X[(size_t)(r0 + rr) * IN_C + k0 + kq * 4];
            x_s[rr][kq * 4 + 0] = v.x; x_s[rr][kq * 4 + 1] = v.y;
            x_s[rr][kq * 4 + 2] = v.z; x_s[rr][kq * 4 + 3] = v.w;
        }
        for (int i4 = tid; i4 < 1024; i4 += 256) {   // stage W 32x128
            int kk = i4 >> 5, cq = i4 & 31;
            float4 v = *(const float4*)&W[(size_t)(k0 + kk) * HID + cq * 4];
            *(float4*)&w_s[kk][cq * 4] = v;
        }
        __syncthreads();
#pragma unroll 8
        for (int kk = 0; kk < 32; ++kk) {
            float x0 = x_s[rg * 2 + 0][kk], x1 = x_s[rg * 2 + 1][kk];
            float4 wa = *(const float4*)&w_s[kk][cg * 4];
            float4 wb = *(const float4*)&w_s[kk][64 + cg * 4];
            acc[0][0] += x0 * wa.x; acc[0][1] += x0 * wa.y; acc[0][2] += x0 * wa.z; acc[0][3] += x0 * wa.w;
            acc[0][4] += x0 * wb.x; acc[0][5] += x0 * wb.y; acc[0][6] += x0 * wb.z; acc[0][7] += x0 * wb.w;
            acc[1][0] += x1 * wa.x; acc[1][1] += x1 * wa.y; acc[1][2] += x1 * wa.z; acc[1][3] += x1 * wa.w;
            acc[1][4] += x1 * wb.x; acc[1][5] += x1 * wb.y; acc[1][6] += x1 * wb.z; acc[1][7] += x1 * wb.w;
        }
    }
    float bv[8];
#pragma unroll
    for (int j = 0; j < 8; ++j) {
        int c = (j < 4) ? (cg * 4 + j) : (64 + cg * 4 + (j - 4));
        bv[j] = B[c];
    }
    if (cfg == 0 || cfg == 2) {
#pragma unroll
        for (int i = 0; i < 2; ++i) {
            int r = r0 + rg * 2 + i;
            float va[8];
#pragma unroll
            for (int j = 0; j < 8; ++j) va[j] = acc[i][j] + bv[j];
            ushort4 h0, l0, h1, l1;
            h0.x = f2bf(va[0]); h0.y = f2bf(va[1]); h0.z = f2bf(va[2]); h0.w = f2bf(va[3]);
            h1.x = f2bf(va[4]); h1.y = f2bf(va[5]); h1.z = f2bf(va[6]); h1.w = f2bf(va[7]);
            l0.x = f2bf(va[0] - bf2f(h0.x)); l0.y = f2bf(va[1] - bf2f(h0.y));
            l0.z = f2bf(va[2] - bf2f(h0.z)); l0.w = f2bf(va[3] - bf2f(h0.w));
            l1.x = f2bf(va[4] - bf2f(h1.x)); l1.y = f2bf(va[5] - bf2f(h1.y));
            l1.z = f2bf(va[6] - bf2f(h1.z)); l1.w = f2bf(va[7] - bf2f(h1.w));
            if (cfg == 0) {
                size_t o0 = (size_t)r * 64 + cg * 4;
                size_t o1 = (size_t)(N_RNA + r) * 64 + cg * 4;
                *(ushort4*)&qhi[o0] = h0; *(ushort4*)&qhi[o1] = h1;
                *(ushort4*)&qlo[o0] = l0; *(ushort4*)&qlo[o1] = l1;
            } else {
                int at = r >> 4, n = r & 15;
                int kc = cg >> 1, ee = (cg & 1) * 4;
                size_t o0 = ((size_t)(at) * 8 + kc) * 128 + n * 8 + ee;
                size_t o1 = ((size_t)(512 + at) * 8 + kc) * 128 + n * 8 + ee;
                *(ushort4*)&khf_hi[o0] = h0; *(ushort4*)&khf_hi[o1] = h1;
                *(ushort4*)&khf_lo[o0] = l0; *(ushort4*)&khf_lo[o1] = l1;
            }
        }
    } else {
        float* C = (cfg == 1) ? v_r : v_a;
#pragma unroll
        for (int i = 0; i < 2; ++i) {
            int r = r0 + rg * 2 + i;
            float4 oa = make_float4(acc[i][0] + bv[0], acc[i][1] + bv[1], acc[i][2] + bv[2], acc[i][3] + bv[3]);
            float4 ob = make_float4(acc[i][4] + bv[4], acc[i][5] + bv[5], acc[i][6] + bv[6], acc[i][7] + bv[7]);
            *(float4*)&C[(size_t)r * HID + cg * 4] = oa;
            *(float4*)&C[(size_t)r * HID + 64 + cg * 4] = ob;
        }
    }
}

// ---------------------------------------------------------------- K1: two-phase MFMA attention
// grid (16 = h*8+chunk, 128 rtiles of 32 rows), block 256 (4 waves).
// blockIdx.x fastest -> linear%8 = chunk pins each a-chunk's K+bits slice (~1 MB)
// to one XCD L2; q streams via L3.  32-row body fits 64 VGPR (no spill).
// Top-10 tau selection is wave-parallel: 8 lanes/row hold 8 bucket maxes each in
// registers; 10 rounds of {lane-max over 8, shfl_xor reduce over 8-lane group,
// winner clears}.  Value-identical to the serial 10x64 scan (tie-break = lowest
// column, and the 10th-largest value is tie-invariant).
__global__ __launch_bounds__(256, 4) void attn2(
    const unsigned short* __restrict__ qhi, const unsigned short* __restrict__ qlo,
    const unsigned short* __restrict__ khf_hi, const unsigned short* __restrict__ khf_lo,
    const unsigned int* __restrict__ bits2,
    int* __restrict__ scnt, float* __restrict__ sval, int* __restrict__ sidx) {
    int hq = blockIdx.x; int h = hq >> 3, chunk = hq & 7;
    int rt = blockIdx.y; int r0 = rt * 32;
    int tid = threadIdx.x;
    int w = tid >> 6, lane = tid & 63;
    int n = lane & 15, quad = lane >> 4;
    int q4 = quad * 4;
    int at0 = chunk * 64 + w * 16;          // a-tile base (16 a per tile)
    int hbase = h * 512;
    int rt64 = rt >> 1, word = rt & 1;

    __shared__ __align__(16) float smem[32 * 65];   // bmax [32][65]; reused: lval[32][32] | lidx[32][32]
    __shared__ float taus[32];
    __shared__ int   lcnt[32];

    const bf16x8* kh8 = (const bf16x8*)khf_hi;
    const bf16x8* kl8 = (const bf16x8*)khf_lo;

    // Preload A-frags: 2 m-tiles x 2 k-chunks, hi+lo
    bf16x8 Ah[2][2], Al[2][2];
#pragma unroll
    for (int mt = 0; mt < 2; ++mt)
#pragma unroll
        for (int c = 0; c < 2; ++c) {
            size_t off = ((size_t)h * N_RNA + r0 + mt * 16 + n) * 64 + c * 32 + quad * 8;
            Ah[mt][c] = *(const bf16x8*)(qhi + off);
            Al[mt][c] = *(const bf16x8*)(qlo + off);
        }

    float mx[2][4];
#pragma unroll
    for (int mt = 0; mt < 2; ++mt)
#pragma unroll
        for (int i = 0; i < 4; ++i) mx[mt][i] = 0.f;

    // ---------------- phase A: approximate (hi*hi) bucket maxes ----------------
#pragma unroll 2
    for (int t = 0; t < 16; ++t) {
        int at = at0 + t;
        size_t bidx = ((size_t)hbase + at) * 128 + lane;
        bf16x8 Bh0 = kh8[bidx];
        bf16x8 Bh1 = kh8[bidx + 64];
        unsigned int bw = bits2[((size_t)rt64 * N_ATAC + at * 16 + n) * 2 + word];

        f32x4 S[2];
#pragma unroll
        for (int mt = 0; mt < 2; ++mt) {
            f32x4 s = {0.f, 0.f, 0.f, 0.f};
            s = mfma16(Ah[mt][0], Bh0, s);
            s = mfma16(Ah[mt][1], Bh1, s);
            S[mt] = s;
        }
#pragma unroll
        for (int mt = 0; mt < 2; ++mt) {
            unsigned int sh = bw >> ((mt << 4) + q4);
#pragma unroll
            for (int i = 0; i < 4; ++i) {
                float v = ((sh >> i) & 1) ? S[mt][i] : 0.f;
                mx[mt][i] = fmaxf(mx[mt][i], v);
            }
        }
    }

    {
        int b = w * 16 + n;
#pragma unroll
        for (int mt = 0; mt < 2; ++mt)
#pragma unroll
            for (int i = 0; i < 4; ++i) smem[(mt * 16 + q4 + i) * 65 + b] = mx[mt][i];
    }
    __syncthreads();
    {   // ---- wave-parallel top-10: 8 lanes per row, values in registers
        int row = tid >> 3, sub = tid & 7;
        float v[8];
#pragma unroll
        for (int j = 0; j < 8; ++j) v[j] = smem[row * 65 + sub * 8 + j];
        float t10 = 0.f;
#pragma unroll
        for (int s = 0; s < 10; ++s) {
            float bv = v[0]; int bj = 0;
#pragma unroll
            for (int j = 1; j < 8; ++j) if (v[j] > bv) { bv = v[j]; bj = j; }
            int meta = (sub << 3) | bj;
#pragma unroll
            for (int off = 1; off < 8; off <<= 1) {
                float ov = __shfl_xor(bv, off);
                int om = __shfl_xor(meta, off);
                if (ov > bv || (ov == bv && om < meta)) { bv = ov; meta = om; }
            }
            if ((meta >> 3) == sub) v[meta & 7] = -1.f;   // winner clears its slot
            t10 = bv;
        }
        if (sub == 0) taus[row] = t10 - TAU_EPS;
        if (tid < 32) lcnt[tid] = 0;
    }
    __syncthreads();

    float tau[2][4];
#pragma unroll
    for (int mt = 0; mt < 2; ++mt)
#pragma unroll
        for (int i = 0; i < 4; ++i) tau[mt][i] = taus[mt * 16 + q4 + i];

    float* lval = smem;                 // [32][CAP]
    int*   lidx = (int*)(smem + 1024);  // [32][CAP]

    // ---------------- phase B: exact scores, collect survivors ----------------
#pragma unroll 2
    for (int t = 0; t < 16; ++t) {
        int at = at0 + t;
        size_t bidx = ((size_t)hbase + at) * 128 + lane;
        bf16x8 Bh0 = kh8[bidx];
        bf16x8 Bh1 = kh8[bidx + 64];
        bf16x8 Bl0 = kl8[bidx];
        bf16x8 Bl1 = kl8[bidx + 64];
        unsigned int bw = bits2[((size_t)rt64 * N_ATAC + at * 16 + n) * 2 + word];

        f32x4 S[2];
#pragma unroll
        for (int mt = 0; mt < 2; ++mt) {
            f32x4 s = {0.f, 0.f, 0.f, 0.f};
            s = mfma16(Ah[mt][0], Bh0, s);
            s = mfma16(Ah[mt][1], Bh1, s);
            s = mfma16(Ah[mt][0], Bl0, s);
            s = mfma16(Ah[mt][1], Bl1, s);
            s = mfma16(Al[mt][0], Bh0, s);
            s = mfma16(Al[mt][1], Bh1, s);
            S[mt] = s;
        }
        int a16 = at * 16 + n;
#pragma unroll
        for (int mt = 0; mt < 2; ++mt) {
            unsigned int sh = bw >> ((mt << 4) + q4);
#pragma unroll
            for (int i = 0; i < 4; ++i) {
                if (((sh >> i) & 1) && S[mt][i] >= tau[mt][i]) {
                    int row = mt * 16 + q4 + i;
                    int pos = atomicAdd(&lcnt[row], 1);
                    if (pos < CAP) { lval[row * CAP + pos] = S[mt][i]; lidx[row * CAP + pos] = a16; }
                }
            }
        }
    }
    __syncthreads();

    // bulk write: block exclusively owns slot ((h*4096 + r)*8 + chunk)
    if (tid < 32) {
        int c = lcnt[tid]; if (c > CAP) c = CAP;
        scnt[((size_t)h * N_RNA + r0 + tid) * NCHUNK + chunk] = c;
    }
    {
        int row = tid >> 3, j0 = tid & 7;
        int c = lcnt[row]; if (c > CAP) c = CAP;
        size_t slot = ((size_t)h * N_RNA + r0 + row) * NCHUNK + chunk;
        for (int j = j0; j < c; j += 8) {
            sval[slot * CAP + j] = lval[row * CAP + j];
            sidx[slot * CAP + j] = lidx[row * CAP + j];
        }
    }
}

// ---------------------------------------------------------------- K2: fused finalize + gather + scatter
__global__ __launch_bounds__(256) void fin_agg(
    const int* __restrict__ scnt, const float* __restrict__ sval, const int* __restrict__ sidx,
    const float* __restrict__ v_a, const float* __restrict__ v_r,
    float* __restrict__ rna_agg, float* __restrict__ atac_agg) {
    int wid = threadIdx.x >> 6, lane = threadIdx.x & 63;
    int p = blockIdx.x * 4 + wid;          // (h*4096 + r)
    int h = p >> 12, r = p & 4095;
    size_t sbase = (size_t)p * NCHUNK;

    float val[4]; int aidx[4];
#pragma unroll
    for (int j = 0; j < 4; ++j) {
        int e = j * 64 + lane;
        int chunk = e >> 5, pos = e & 31;
        int c = scnt[sbase + chunk];
        size_t sl = (sbase + chunk) * CAP + pos;
        bool ok = pos < c;
        val[j] = ok ? sval[sl] : NEG_INF;
        aidx[j] = ok ? sidx[sl] : 0;
    }

    float sv[10]; int si[10];
#pragma unroll
    for (int s = 0; s < 10; ++s) {
        float bv = val[0]; int bj = 0;
#pragma unroll
        for (int j = 1; j < 4; ++j) if (val[j] > bv) { bv = val[j]; bj = j; }
        int bmeta = (bj << 6) | lane;
#pragma unroll
        for (int off = 32; off >= 1; off >>= 1) {
            float ov = __shfl_xor(bv, off);
            int om = __shfl_xor(bmeta, off);
            if (ov > bv || (ov == bv && om < bmeta)) { bv = ov; bmeta = om; }
        }
        int wj = bmeta >> 6, wl = bmeta & 63;
        if (lane == wl) {
#pragma unroll
            for (int j = 0; j < 4; ++j) if (j == wj) val[j] = NEG_INF;
        }
        int av = aidx[0];
#pragma unroll
        for (int j = 1; j < 4; ++j) if (wj == j) av = aidx[j];
        sv[s] = bv;
        si[s] = __shfl(av, wl);
    }

    float wgt[10]; float sum = 0.f; float sg[10];
#pragma unroll
    for (int s = 0; s < 10; ++s) {
        sg[s] = 1.0f / (1.0f + expf(-sv[s]));
        float es = expf(sg[s]);
        wgt[s] = es;
        sum += es;
    }
    float inv = 1.0f / sum;
#pragma unroll
    for (int s = 0; s < 10; ++s) {
        wgt[s] *= inv;
        if (!(sg[s] > 0.8f)) wgt[s] = 0.f;
    }

    float acc = 0.f;
#pragma unroll
    for (int s = 0; s < 10; ++s) {
        float vv = v_a[(size_t)si[s] * HID + h * 64 + lane];
        acc += wgt[s] * vv;
    }
    rna_agg[(size_t)r * HID + h * 64 + lane] = acc;

    float vr = v_r[(size_t)r * HID + h * 64 + lane];
#pragma unroll
    for (int s = 0; s < 10; ++s) {
        if (wgt[s] != 0.f) {
            atomicAdd(&atac_agg[(size_t)si[s] * HID + h * 64 + lane], wgt[s] * vr);
        }
    }
}

// ---------------------------------------------------------------- K3: out = [Agg|X] @ [W1;W2] + bias, LDS-tiled
__global__ __launch_bounds__(256) void out_gemm(
    const float* __restrict__ rna_agg, const float* __restrict__ x_rna,
    const float* __restrict__ Wr1, const float* __restrict__ Wr2, const float* __restrict__ brf,
    const float* __restrict__ atac_agg, const float* __restrict__ x_atac,
    const float* __restrict__ Wa1, const float* __restrict__ Wa2, const float* __restrict__ baf,
    float* __restrict__ out_r, float* __restrict__ out_a) {
    __shared__ __align__(16) float x_s[32][33];
    __shared__ __align__(16) float w_s[32][128];
    int bx = blockIdx.x;
    const float *A, *X, *W1, *W2, *bias; float* C;
    int r0;
    if (bx < 128) { A = rna_agg; X = x_rna; W1 = Wr1; W2 = Wr2; bias = brf; C = out_r; r0 = bx * 32; }
    else { A = atac_agg; X = x_atac; W1 = Wa1; W2 = Wa2; bias = baf; C = out_a; r0 = (bx - 128) * 32; }
    int tid = threadIdx.x;
    int rg = tid >> 4, cg = tid & 15;

    float acc[2][8];
#pragma unroll
    for (int i = 0; i < 2; ++i)
#pragma unroll
        for (int j = 0; j < 8; ++j) acc[i][j] = 0.f;

    for (int k0 = 0; k0 < 384; k0 += 32) {
        __syncthreads();
        {
            int rr = tid >> 3, kq = tid & 7;
            float4 v;
            if (k0 < 128) v = *(const float4*)&A[(size_t)(r0 + rr) * HID + k0 + kq * 4];
            else          v = *(const float4*)&X[(size_t)(r0 + rr) * IN_C + (k0 - 128) + kq * 4];
            x_s[rr][kq * 4 + 0] = v.x; x_s[rr][kq * 4 + 1] = v.y;
            x_s[rr][kq * 4 + 2] = v.z; x_s[rr][kq * 4 + 3] = v.w;
        }
        for (int i4 = tid; i4 < 1024; i4 += 256) {
            int kk = i4 >> 5, cq = i4 & 31;
            float4 v;
            if (k0 < 128) v = *(const float4*)&W1[(size_t)(k0 + kk) * HID + cq * 4];
            else          v = *(const float4*)&W2[(size_t)(k0 - 128 + kk) * HID + cq * 4];
            *(float4*)&w_s[kk][cq * 4] = v;
        }
        __syncthreads();
#pragma unroll 8
        for (int kk = 0; kk < 32; ++kk) {
            float x0 = x_s[rg * 2 + 0][kk], x1 = x_s[rg * 2 + 1][kk];
            float4 wa = *(const float4*)&w_s[kk][cg * 4];
            float4 wb = *(const float4*)&w_s[kk][64 + cg * 4];
            acc[0][0] += x0 * wa.x; acc[0][1] += x0 * wa.y; acc[0][2] += x0 * wa.z; acc[0][3] += x0 * wa.w;
            acc[0][4] += x0 * wb.x; acc[0][5] += x0 * wb.y; acc[0][6] += x0 * wb.z; acc[0][7] += x0 * wb.w;
            acc[1][0] += x1 * wa.x; acc[1][1] += x1 * wa.y; acc[1][2] += x1 * wa.z; acc[1][3] += x1 * wa.w;
            acc[1][4] += x1 * wb.x; acc[1][5] += x1 * wb.y; acc[1][6] += x1 * wb.z; acc[1][7] += x1 * wb.w;
        }
    }
    float bv[8];
#pragma unroll
    for (int j = 0; j < 8; ++j) {
        int c = (j < 4) ? (cg * 4 + j) : (64 + cg * 4 + (j - 4));
        bv[j] = bias[c];
    }
#pragma unroll
    for (int i = 0; i < 2; ++i) {
        int r = r0 + rg * 2 + i;
        float4 oa = make_float4(acc[i][0] + bv[0], acc[i][1] + bv[1], acc[i][2] + bv[2], acc[i][3] + bv[3]);
        float4 ob = make_float4(acc[i][4] + bv[4], acc[i][5] + bv[5], acc[i][6] + bv[6], acc[i][7] + bv[7]);
        *(float4*)&C[(size_t)r * HID + cg * 4] = oa;
        *(float4*)&C[(size_t)r * HID + 64 + cg * 4] = ob;
    }
}

// ---------------------------------------------------------------- launch
extern "C" void kernel_launch(void* const* d_in, const int* in_sizes, int n_in,
                              void* d_out, int out_size, void* d_ws, size_t ws_size,
                              hipStream_t stream) {
    const float* x_rna = (const float*)d_in[0];
    const float* x_atac = (const float*)d_in[1];
    const float* mask = (const float*)d_in[2];
    const float* Wq = (const float*)d_in[3];  const float* bq = (const float*)d_in[4];
    const float* Wk = (const float*)d_in[5];  const float* bk = (const float*)d_in[6];
    const float* Wvr = (const float*)d_in[7]; const float* bvr = (const float*)d_in[8];
    const float* Wva = (const float*)d_in[9]; const float* bva = (const float*)d_in[10];
    const float* Wor = (const float*)d_in[11]; const float* bor = (const float*)d_in[12];
    const float* Woa = (const float*)d_in[13]; const float* boa = (const float*)d_in[14];
    const float* Wsr = (const float*)d_in[15]; const float* bsr = (const float*)d_in[16];
    const float* Wsa = (const float*)d_in[17]; const float* bsa = (const float*)d_in[18];
    const float* Wdr = (const float*)d_in[19]; const float* bdr = (const float*)d_in[20];
    const float* Wda = (const float*)d_in[21]; const float* bda = (const float*)d_in[22];

    float* out_r = (float*)d_out;
    float* out_a = out_r + N_RNA * HID;

    float* ws = (float*)d_ws;
    unsigned short* qhi = (unsigned short*)ws;            // 2*4096*64 us
    unsigned short* qlo = qhi + 524288;
    unsigned short* khf_hi = qlo + 524288;                // 2*8192*64 us (frag layout)
    unsigned short* khf_lo = khf_hi + 1048576;
    unsigned int* bits2 = (unsigned int*)(ws + 1572864);  // 64*8192*2 uint
    float* v_r = ws + 1572864 + 1048576;                  // 4096x128
    float* v_a = v_r + 524288;                            // 8192x128
    float* Wr1 = v_a + 1048576;                           // 128x128
    float* Wr2 = Wr1 + 16384;                             // 256x128
    float* brf = Wr2 + 32768;                             // 128
    float* Wa1 = brf + 128;                               // 128x128
    float* Wa2 = Wa1 + 16384;                             // 256x128
    float* baf = Wa2 + 32768;                             // 128
    int* scnt = (int*)(baf + 128);                        // 8192*8 ints
    float* sval = (float*)scnt + 65536;                   // 65536*32
    int* sidx = (int*)(sval + 2097152);                   // 65536*32
    float* rna_agg = (float*)sidx + 2097152;              // 4096x128
    float* atac_agg = rna_agg + 524288;                   // 8192x128

    hipLaunchKernelGGL(prep_all, dim3(2434), dim3(256), 0, stream,
                       mask, bits2, atac_agg,
                       Wor, bor, Woa, boa, Wsr, bsr, Wsa, bsa, Wdr, bdr, Wda, bda,
                       Wr1, Wr2, brf, Wa1, Wa2, baf,
                       x_rna, x_atac, Wq, bq, Wk, bk, Wvr, bvr, Wva, bva,
                       qhi, qlo, khf_hi, khf_lo, v_r, v_a);
    hipLaunchKernelGGL(attn2, dim3(16, 128), dim3(256), 0, stream,
                       qhi, qlo, khf_hi, khf_lo, bits2, scnt, sval, sidx);
    hipLaunchKernelGGL(fin_agg, dim3(2048), dim3(256), 0, stream,
                       scnt, sval, sidx, v_a, v_r, rna_agg, atac_agg);
    hipLaunchKernelGGL(out_gemm, dim3(384), dim3(256), 0, stream,
                       rna_agg, x_rna, Wr1, Wr2, brf,
                       atac_agg, x_atac, Wa1, Wa2, baf, out_r, out_a);
}

// Round 2
// 380.816 us; speedup vs baseline: 1.1041x; 1.1041x over previous
//
#include <hip/hip_runtime.h>
#include <math.h>

#define N_RNA 4096
#define N_ATAC 8192
#define IN_C 256
#define HID 128
#define NH 2
#define TOPK 10
#define CAP 32
#define NCHUNK 8
#define TAU_EPS 0.12f
#define NEG_INF -3.402823466e38f

typedef __attribute__((ext_vector_type(8))) short bf16x8;
typedef __attribute__((ext_vector_type(4))) float f32x4;

static __device__ __forceinline__ f32x4 mfma16(bf16x8 a, bf16x8 b, f32x4 c) {
    return __builtin_amdgcn_mfma_f32_16x16x32_bf16(a, b, c, 0, 0, 0);
}

static __device__ __forceinline__ unsigned short f2bf(float f) {
    unsigned int u = __float_as_uint(f);
    unsigned int r = (u + 0x7fffu + ((u >> 16) & 1u)) >> 16;   // RNE
    return (unsigned short)r;
}
static __device__ __forceinline__ float bf2f(unsigned short h) {
    return __uint_as_float(((unsigned int)h) << 16);
}

// ---------------------------------------------------------------- K0a: wprep
// [0,32): transpose proj weights -> frag-contiguous bf16 hi/lo [col][k].
// [32,417): fuse output weights -> transposed bf16 hi/lo + fp32 fused bias.
__global__ __launch_bounds__(256) void wprep(
    const float* __restrict__ Wq, const float* __restrict__ Wk,
    const float* __restrict__ Wvr, const float* __restrict__ Wva,
    const float* __restrict__ Wor, const float* __restrict__ bor,
    const float* __restrict__ Woa, const float* __restrict__ boa,
    const float* __restrict__ Wsr, const float* __restrict__ bsr,
    const float* __restrict__ Wsa, const float* __restrict__ bsa,
    const float* __restrict__ Wdr, const float* __restrict__ bdr,
    const float* __restrict__ Wda, const float* __restrict__ bda,
    unsigned short* __restrict__ wt, unsigned short* __restrict__ wrf,
    unsigned short* __restrict__ waf,
    float* __restrict__ brf, float* __restrict__ baf) {
    int bx = blockIdx.x, tid = threadIdx.x;
    if (bx < 32) {                          // ---- proj weight transpose+convert
        int cfg = bx >> 3, k0 = (bx & 7) * 32;
        const float* W = (cfg == 0) ? Wq : (cfg == 1) ? Wvr : (cfg == 2) ? Wk : Wva;
        __shared__ float ts[32][132];
#pragma unroll
        for (int rep = 0; rep < 4; ++rep) {
            int id = rep * 256 + tid; int kk = id >> 5, cq = id & 31;
            float4 v = *(const float4*)&W[(size_t)(k0 + kk) * HID + cq * 4];
            ts[kk][cq * 4 + 0] = v.x; ts[kk][cq * 4 + 1] = v.y;
            ts[kk][cq * 4 + 2] = v.z; ts[kk][cq * 4 + 3] = v.w;
        }
        __syncthreads();
        int col = tid >> 1, seg = tid & 1;
        unsigned short hb[16], lb[16];
#pragma unroll
        for (int u = 0; u < 16; ++u) {
            float f = ts[seg * 16 + u][col];
            unsigned short h = f2bf(f);
            hb[u] = h; lb[u] = f2bf(f - bf2f(h));
        }
        unsigned short* hp = wt + cfg * 65536;
        unsigned short* lp = hp + 32768;
        size_t o = (size_t)col * 256 + k0 + seg * 16;
#pragma unroll
        for (int u4 = 0; u4 < 4; ++u4) {
            ushort4 th, tl;
            th.x = hb[u4 * 4]; th.y = hb[u4 * 4 + 1]; th.z = hb[u4 * 4 + 2]; th.w = hb[u4 * 4 + 3];
            tl.x = lb[u4 * 4]; tl.y = lb[u4 * 4 + 1]; tl.z = lb[u4 * 4 + 2]; tl.w = lb[u4 * 4 + 3];
            *(ushort4*)&hp[o + u4 * 4] = th;
            *(ushort4*)&lp[o + u4 * 4] = tl;
        }
        return;
    }
    // ---- fuse weights (transposed bf16 hi/lo out)
    int f = (bx - 32) * 256 + tid;
    if (f < 16384) {
        int i = f >> 7, j = f & 127; float s = 0.f;
        for (int t = 0; t < 128; ++t) s += Wor[i * 128 + t] * Wdr[t * 128 + j];
        unsigned short h = f2bf(s);
        wrf[(size_t)j * 128 + i] = h;
        wrf[16384 + (size_t)j * 128 + i] = f2bf(s - bf2f(h));
    } else if (f < 49152) {
        int e = f - 16384; int i = e >> 7, j = e & 127; float s = 0.f;
        for (int t = 0; t < 128; ++t) s += Wsr[i * 128 + t] * Wdr[(128 + t) * 128 + j];
        unsigned short h = f2bf(s);
        wrf[32768 + (size_t)j * 256 + i] = h;
        wrf[65536 + (size_t)j * 256 + i] = f2bf(s - bf2f(h));
    } else if (f < 65536) {
        int e = f - 49152; int i = e >> 7, j = e & 127; float s = 0.f;
        for (int t = 0; t < 128; ++t) s += Woa[i * 128 + t] * Wda[t * 128 + j];
        unsigned short h = f2bf(s);
        waf[(size_t)j * 128 + i] = h;
        waf[16384 + (size_t)j * 128 + i] = f2bf(s - bf2f(h));
    } else if (f < 98304) {
        int e = f - 65536; int i = e >> 7, j = e & 127; float s = 0.f;
        for (int t = 0; t < 128; ++t) s += Wsa[i * 128 + t] * Wda[(128 + t) * 128 + j];
        unsigned short h = f2bf(s);
        waf[32768 + (size_t)j * 256 + i] = h;
        waf[65536 + (size_t)j * 256 + i] = f2bf(s - bf2f(h));
    } else if (f < 98432) {
        int j = f - 98304; float s = bdr[j];
        for (int t = 0; t < 128; ++t) s += bor[t] * Wdr[t * 128 + j] + bsr[t] * Wdr[(128 + t) * 128 + j];
        brf[j] = s;
    } else if (f < 98560) {
        int j = f - 98432; float s = bda[j];
        for (int t = 0; t < 128; ++t) s += boa[t] * Wda[t * 128 + j] + bsa[t] * Wda[(128 + t) * 128 + j];
        baf[j] = s;
    }
}

// ---------------------------------------------------------------- K0b: prep_all
// [0,768): MFMA split-bf16 projections (32-row x 128-col tiles, K=256).
// [768,1280): mask->bits2 (float4, 4 a/thr).  [1280,1536): zero atac_agg.
__global__ __launch_bounds__(256) void prep_all(
    const float* __restrict__ mask, unsigned int* __restrict__ bits2,
    float* __restrict__ atac_agg,
    const float* __restrict__ x_rna, const float* __restrict__ x_atac,
    const unsigned short* __restrict__ wt,
    const float* __restrict__ bq, const float* __restrict__ bk,
    const float* __restrict__ bvr, const float* __restrict__ bva,
    unsigned short* __restrict__ qhi, unsigned short* __restrict__ qlo,
    unsigned short* __restrict__ khf_hi, unsigned short* __restrict__ khf_lo,
    float* __restrict__ v_r, float* __restrict__ v_a) {
    __shared__ __align__(16) unsigned short ah_s[32 * 40];
    __shared__ __align__(16) unsigned short al_s[32 * 40];
    int bx = blockIdx.x, tid = threadIdx.x;

    if (bx >= 768 && bx < 1280) {                 // ---- mask -> bits2, float4
        int e = bx - 768;
        int rt = e >> 3, ac = e & 7;
        int a0 = ac * 1024 + tid * 4;
        int r0 = rt * 64;
        unsigned int w0[4] = {0, 0, 0, 0}, w1[4] = {0, 0, 0, 0};
#pragma unroll 8
        for (int rr = 0; rr < 32; ++rr) {
            float4 m0 = *(const float4*)&mask[(size_t)(r0 + rr) * N_ATAC + a0];
            float4 m1 = *(const float4*)&mask[(size_t)(r0 + 32 + rr) * N_ATAC + a0];
            w0[0] |= ((m0.x > 0.5f) ? 1u : 0u) << rr;
            w0[1] |= ((m0.y > 0.5f) ? 1u : 0u) << rr;
            w0[2] |= ((m0.z > 0.5f) ? 1u : 0u) << rr;
            w0[3] |= ((m0.w > 0.5f) ? 1u : 0u) << rr;
            w1[0] |= ((m1.x > 0.5f) ? 1u : 0u) << rr;
            w1[1] |= ((m1.y > 0.5f) ? 1u : 0u) << rr;
            w1[2] |= ((m1.z > 0.5f) ? 1u : 0u) << rr;
            w1[3] |= ((m1.w > 0.5f) ? 1u : 0u) << rr;
        }
        uint4 oA = make_uint4(w0[0], w1[0], w0[1], w1[1]);
        uint4 oB = make_uint4(w0[2], w1[2], w0[3], w1[3]);
        *(uint4*)&bits2[((size_t)rt * N_ATAC + a0) * 2] = oA;
        *(uint4*)&bits2[((size_t)rt * N_ATAC + a0) * 2 + 4] = oB;
        return;
    }
    if (bx >= 1280) {                             // ---- zero atac_agg (64 B/thread)
        size_t i = ((size_t)(bx - 1280) * 256 + tid) * 16;
        float4 z = make_float4(0.f, 0.f, 0.f, 0.f);
        *(float4*)&atac_agg[i] = z;
        *(float4*)&atac_agg[i + 4] = z;
        *(float4*)&atac_agg[i + 8] = z;
        *(float4*)&atac_agg[i + 12] = z;
        return;
    }

    // ---- projections via split-bf16 MFMA (3-term hi/lo)
    int cfg, rblk;
    if (bx < 128)      { cfg = 0; rblk = bx; }
    else if (bx < 256) { cfg = 1; rblk = bx - 128; }
    else if (bx < 512) { cfg = 2; rblk = bx - 256; }
    else               { cfg = 3; rblk = bx - 512; }
    const float* X = (cfg <= 1) ? x_rna : x_atac;
    const float* Bv = (cfg == 0) ? bq : (cfg == 1) ? bvr : (cfg == 2) ? bk : bva;
    const unsigned short* wth = wt + cfg * 65536;
    const unsigned short* wtl = wth + 32768;
    int r0 = rblk * 32;
    int w = tid >> 6, lane = tid & 63, n = lane & 15, quad = lane >> 4;

    const f32x4 zf = {0.f, 0.f, 0.f, 0.f};
    f32x4 acc[2][2];
#pragma unroll
    for (int mt = 0; mt < 2; ++mt)
#pragma unroll
        for (int nt = 0; nt < 2; ++nt) acc[mt][nt] = zf;

    for (int k0 = 0; k0 < IN_C; k0 += 32) {
        __syncthreads();
        {   // stage X 32x32 -> bf16 hi/lo, 40-elem padded rows (2-way-free banks)
            int rr = tid >> 3, kq = tid & 7;
            float4 v = *(const float4*)&X[(size_t)(r0 + rr) * IN_C + k0 + kq * 4];
            ushort4 h, l;
            h.x = f2bf(v.x); h.y = f2bf(v.y); h.z = f2bf(v.z); h.w = f2bf(v.w);
            l.x = f2bf(v.x - bf2f(h.x)); l.y = f2bf(v.y - bf2f(h.y));
            l.z = f2bf(v.z - bf2f(h.z)); l.w = f2bf(v.w - bf2f(h.w));
            *(ushort4*)&ah_s[rr * 40 + kq * 4] = h;
            *(ushort4*)&al_s[rr * 40 + kq * 4] = l;
        }
        __syncthreads();
        bf16x8 Afh[2], Afl[2];
#pragma unroll
        for (int mt = 0; mt < 2; ++mt) {
            Afh[mt] = *(const bf16x8*)&ah_s[(mt * 16 + n) * 40 + quad * 8];
            Afl[mt] = *(const bf16x8*)&al_s[(mt * 16 + n) * 40 + quad * 8];
        }
#pragma unroll
        for (int nt = 0; nt < 2; ++nt) {
            int c = w * 32 + nt * 16 + n;
            size_t o = (size_t)c * 256 + k0 + quad * 8;
            bf16x8 Bh = *(const bf16x8*)&wth[o];
            bf16x8 Bl = *(const bf16x8*)&wtl[o];
#pragma unroll
            for (int mt = 0; mt < 2; ++mt) {
                acc[mt][nt] = mfma16(Afh[mt], Bh, acc[mt][nt]);
                acc[mt][nt] = mfma16(Afh[mt], Bl, acc[mt][nt]);
                acc[mt][nt] = mfma16(Afl[mt], Bh, acc[mt][nt]);
            }
        }
    }
    float bvx[2];
    bvx[0] = Bv[w * 32 + n]; bvx[1] = Bv[w * 32 + 16 + n];
    // C layout: col = lane&15, row = quad*4 + i (verified m89/m91)
    if (cfg == 1 || cfg == 3) {
        float* C = (cfg == 1) ? v_r : v_a;
#pragma unroll
        for (int mt = 0; mt < 2; ++mt)
#pragma unroll
            for (int nt = 0; nt < 2; ++nt)
#pragma unroll
                for (int i = 0; i < 4; ++i) {
                    int r = r0 + mt * 16 + quad * 4 + i;
                    int c = w * 32 + nt * 16 + n;
                    C[(size_t)r * HID + c] = acc[mt][nt][i] + bvx[nt];
                }
    } else if (cfg == 0) {
#pragma unroll
        for (int mt = 0; mt < 2; ++mt)
#pragma unroll
            for (int nt = 0; nt < 2; ++nt)
#pragma unroll
                for (int i = 0; i < 4; ++i) {
                    int r = r0 + mt * 16 + quad * 4 + i;
                    int c = w * 32 + nt * 16 + n;
                    float o = acc[mt][nt][i] + bvx[nt];
                    int head = c >> 6, ch = c & 63;
                    size_t off = ((size_t)head * N_RNA + r) * 64 + ch;
                    unsigned short h = f2bf(o);
                    qhi[off] = h; qlo[off] = f2bf(o - bf2f(h));
                }
    } else {    // cfg == 2: k frag layout
#pragma unroll
        for (int mt = 0; mt < 2; ++mt)
#pragma unroll
            for (int nt = 0; nt < 2; ++nt)
#pragma unroll
                for (int i = 0; i < 4; ++i) {
                    int r = r0 + mt * 16 + quad * 4 + i;
                    int c = w * 32 + nt * 16 + n;
                    float o = acc[mt][nt][i] + bvx[nt];
                    int head = c >> 6, ch = c & 63;
                    size_t off = ((size_t)(head * 512 + (r >> 4)) * 8 + (ch >> 3)) * 128
                               + (size_t)(r & 15) * 8 + (ch & 7);
                    unsigned short h = f2bf(o);
                    khf_hi[off] = h; khf_lo[off] = f2bf(o - bf2f(h));
                }
    }
}

// ---------------------------------------------------------------- K1: two-phase MFMA attention
// grid (16 = h*8+chunk, 128 rtiles of 32 rows), block 256 (4 waves).
// blockIdx.x fastest -> linear%8 = chunk pins each a-chunk's K+bits slice (~1 MB)
// to one XCD L2; q streams via L3.  Wave-parallel top-10 tau selection.
__global__ __launch_bounds__(256, 4) void attn2(
    const unsigned short* __restrict__ qhi, const unsigned short* __restrict__ qlo,
    const unsigned short* __restrict__ khf_hi, const unsigned short* __restrict__ khf_lo,
    const unsigned int* __restrict__ bits2,
    int* __restrict__ scnt, float* __restrict__ sval, int* __restrict__ sidx) {
    int hq = blockIdx.x; int h = hq >> 3, chunk = hq & 7;
    int rt = blockIdx.y; int r0 = rt * 32;
    int tid = threadIdx.x;
    int w = tid >> 6, lane = tid & 63;
    int n = lane & 15, quad = lane >> 4;
    int q4 = quad * 4;
    int at0 = chunk * 64 + w * 16;          // a-tile base (16 a per tile)
    int hbase = h * 512;
    int rt64 = rt >> 1, word = rt & 1;

    __shared__ __align__(16) float smem[32 * 65];   // bmax [32][65]; reused: lval[32][32] | lidx[32][32]
    __shared__ float taus[32];
    __shared__ int   lcnt[32];

    const bf16x8* kh8 = (const bf16x8*)khf_hi;
    const bf16x8* kl8 = (const bf16x8*)khf_lo;

    // Preload A-frags: 2 m-tiles x 2 k-chunks, hi+lo
    bf16x8 Ah[2][2], Al[2][2];
#pragma unroll
    for (int mt = 0; mt < 2; ++mt)
#pragma unroll
        for (int c = 0; c < 2; ++c) {
            size_t off = ((size_t)h * N_RNA + r0 + mt * 16 + n) * 64 + c * 32 + quad * 8;
            Ah[mt][c] = *(const bf16x8*)(qhi + off);
            Al[mt][c] = *(const bf16x8*)(qlo + off);
        }

    float mx[2][4];
#pragma unroll
    for (int mt = 0; mt < 2; ++mt)
#pragma unroll
        for (int i = 0; i < 4; ++i) mx[mt][i] = 0.f;

    // ---------------- phase A: approximate (hi*hi) bucket maxes ----------------
#pragma unroll 2
    for (int t = 0; t < 16; ++t) {
        int at = at0 + t;
        size_t bidx = ((size_t)hbase + at) * 128 + lane;
        bf16x8 Bh0 = kh8[bidx];
        bf16x8 Bh1 = kh8[bidx + 64];
        unsigned int bw = bits2[((size_t)rt64 * N_ATAC + at * 16 + n) * 2 + word];

        f32x4 S[2];
#pragma unroll
        for (int mt = 0; mt < 2; ++mt) {
            f32x4 s = {0.f, 0.f, 0.f, 0.f};
            s = mfma16(Ah[mt][0], Bh0, s);
            s = mfma16(Ah[mt][1], Bh1, s);
            S[mt] = s;
        }
#pragma unroll
        for (int mt = 0; mt < 2; ++mt) {
            unsigned int sh = bw >> ((mt << 4) + q4);
#pragma unroll
            for (int i = 0; i < 4; ++i) {
                float v = ((sh >> i) & 1) ? S[mt][i] : 0.f;
                mx[mt][i] = fmaxf(mx[mt][i], v);
            }
        }
    }

    {
        int b = w * 16 + n;
#pragma unroll
        for (int mt = 0; mt < 2; ++mt)
#pragma unroll
            for (int i = 0; i < 4; ++i) smem[(mt * 16 + q4 + i) * 65 + b] = mx[mt][i];
    }
    __syncthreads();
    {   // ---- wave-parallel top-10: 8 lanes per row, values in registers
        int row = tid >> 3, sub = tid & 7;
        float v[8];
#pragma unroll
        for (int j = 0; j < 8; ++j) v[j] = smem[row * 65 + sub * 8 + j];
        float t10 = 0.f;
#pragma unroll
        for (int s = 0; s < 10; ++s) {
            float bv = v[0]; int bj = 0;
#pragma unroll
            for (int j = 1; j < 8; ++j) if (v[j] > bv) { bv = v[j]; bj = j; }
            int meta = (sub << 3) | bj;
#pragma unroll
            for (int off = 1; off < 8; off <<= 1) {
                float ov = __shfl_xor(bv, off);
                int om = __shfl_xor(meta, off);
                if (ov > bv || (ov == bv && om < meta)) { bv = ov; meta = om; }
            }
            if ((meta >> 3) == sub) v[meta & 7] = -1.f;   // winner clears its slot
            t10 = bv;
        }
        if (sub == 0) taus[row] = t10 - TAU_EPS;
        if (tid < 32) lcnt[tid] = 0;
    }
    __syncthreads();

    float tau[2][4];
#pragma unroll
    for (int mt = 0; mt < 2; ++mt)
#pragma unroll
        for (int i = 0; i < 4; ++i) tau[mt][i] = taus[mt * 16 + q4 + i];

    float* lval = smem;                 // [32][CAP]
    int*   lidx = (int*)(smem + 1024);  // [32][CAP]

    // ---------------- phase B: exact scores, collect survivors ----------------
#pragma unroll 2
    for (int t = 0; t < 16; ++t) {
        int at = at0 + t;
        size_t bidx = ((size_t)hbase + at) * 128 + lane;
        bf16x8 Bh0 = kh8[bidx];
        bf16x8 Bh1 = kh8[bidx + 64];
        bf16x8 Bl0 = kl8[bidx];
        bf16x8 Bl1 = kl8[bidx + 64];
        unsigned int bw = bits2[((size_t)rt64 * N_ATAC + at * 16 + n) * 2 + word];

        f32x4 S[2];
#pragma unroll
        for (int mt = 0; mt < 2; ++mt) {
            f32x4 s = {0.f, 0.f, 0.f, 0.f};
            s = mfma16(Ah[mt][0], Bh0, s);
            s = mfma16(Ah[mt][1], Bh1, s);
            s = mfma16(Ah[mt][0], Bl0, s);
            s = mfma16(Ah[mt][1], Bl1, s);
            s = mfma16(Al[mt][0], Bh0, s);
            s = mfma16(Al[mt][1], Bh1, s);
            S[mt] = s;
        }
        int a16 = at * 16 + n;
#pragma unroll
        for (int mt = 0; mt < 2; ++mt) {
            unsigned int sh = bw >> ((mt << 4) + q4);
#pragma unroll
            for (int i = 0; i < 4; ++i) {
                if (((sh >> i) & 1) && S[mt][i] >= tau[mt][i]) {
                    int row = mt * 16 + q4 + i;
                    int pos = atomicAdd(&lcnt[row], 1);
                    if (pos < CAP) { lval[row * CAP + pos] = S[mt][i]; lidx[row * CAP + pos] = a16; }
                }
            }
        }
    }
    __syncthreads();

    // bulk write: block exclusively owns slot ((h*4096 + r)*8 + chunk)
    if (tid < 32) {
        int c = lcnt[tid]; if (c > CAP) c = CAP;
        scnt[((size_t)h * N_RNA + r0 + tid) * NCHUNK + chunk] = c;
    }
    {
        int row = tid >> 3, j0 = tid & 7;
        int c = lcnt[row]; if (c > CAP) c = CAP;
        size_t slot = ((size_t)h * N_RNA + r0 + row) * NCHUNK + chunk;
        for (int j = j0; j < c; j += 8) {
            sval[slot * CAP + j] = lval[row * CAP + j];
            sidx[slot * CAP + j] = lidx[row * CAP + j];
        }
    }
}

// ---------------------------------------------------------------- K2: fused finalize + gather + scatter
__global__ __launch_bounds__(256) void fin_agg(
    const int* __restrict__ scnt, const float* __restrict__ sval, const int* __restrict__ sidx,
    const float* __restrict__ v_a, const float* __restrict__ v_r,
    float* __restrict__ rna_agg, float* __restrict__ atac_agg) {
    int wid = threadIdx.x >> 6, lane = threadIdx.x & 63;
    int p = blockIdx.x * 4 + wid;          // (h*4096 + r)
    int h = p >> 12, r = p & 4095;
    size_t sbase = (size_t)p * NCHUNK;

    float val[4]; int aidx[4];
#pragma unroll
    for (int j = 0; j < 4; ++j) {
        int e = j * 64 + lane;
        int chunk = e >> 5, pos = e & 31;
        int c = scnt[sbase + chunk];
        size_t sl = (sbase + chunk) * CAP + pos;
        bool ok = pos < c;
        val[j] = ok ? sval[sl] : NEG_INF;
        aidx[j] = ok ? sidx[sl] : 0;
    }

    float sv[10]; int si[10];
#pragma unroll
    for (int s = 0; s < 10; ++s) {
        float bv = val[0]; int bj = 0;
#pragma unroll
        for (int j = 1; j < 4; ++j) if (val[j] > bv) { bv = val[j]; bj = j; }
        int bmeta = (bj << 6) | lane;
#pragma unroll
        for (int off = 32; off >= 1; off >>= 1) {
            float ov = __shfl_xor(bv, off);
            int om = __shfl_xor(bmeta, off);
            if (ov > bv || (ov == bv && om < bmeta)) { bv = ov; bmeta = om; }
        }
        int wj = bmeta >> 6, wl = bmeta & 63;
        if (lane == wl) {
#pragma unroll
            for (int j = 0; j < 4; ++j) if (j == wj) val[j] = NEG_INF;
        }
        int av = aidx[0];
#pragma unroll
        for (int j = 1; j < 4; ++j) if (wj == j) av = aidx[j];
        sv[s] = bv;
        si[s] = __shfl(av, wl);
    }

    float wgt[10]; float sum = 0.f; float sg[10];
#pragma unroll
    for (int s = 0; s < 10; ++s) {
        sg[s] = 1.0f / (1.0f + expf(-sv[s]));
        float es = expf(sg[s]);
        wgt[s] = es;
        sum += es;
    }
    float inv = 1.0f / sum;
#pragma unroll
    for (int s = 0; s < 10; ++s) {
        wgt[s] *= inv;
        if (!(sg[s] > 0.8f)) wgt[s] = 0.f;
    }

    float acc = 0.f;
#pragma unroll
    for (int s = 0; s < 10; ++s) {
        float vv = v_a[(size_t)si[s] * HID + h * 64 + lane];
        acc += wgt[s] * vv;
    }
    rna_agg[(size_t)r * HID + h * 64 + lane] = acc;

    float vr = v_r[(size_t)r * HID + h * 64 + lane];
#pragma unroll
    for (int s = 0; s < 10; ++s) {
        if (wgt[s] != 0.f) {
            atomicAdd(&atac_agg[(size_t)si[s] * HID + h * 64 + lane], wgt[s] * vr);
        }
    }
}

// ---------------------------------------------------------------- K3: out = [Agg|X] @ Wfused + bias, MFMA split-bf16
// B pre-transposed bf16 hi/lo in global (L2-hot): part1 [col][128], part2 [col][256].
__global__ __launch_bounds__(256) void out_gemm(
    const float* __restrict__ rna_agg, const float* __restrict__ x_rna,
    const unsigned short* __restrict__ wrt, const float* __restrict__ brf,
    const float* __restrict__ atac_agg, const float* __restrict__ x_atac,
    const unsigned short* __restrict__ wat, const float* __restrict__ baf,
    float* __restrict__ out_r, float* __restrict__ out_a) {
    __shared__ __align__(16) unsigned short ah_s[32 * 40];
    __shared__ __align__(16) unsigned short al_s[32 * 40];
    int bx = blockIdx.x, tid = threadIdx.x;
    const float *A, *X, *bias; const unsigned short* wb; float* C; int r0;
    if (bx < 128) { A = rna_agg; X = x_rna; wb = wrt; bias = brf; C = out_r; r0 = bx * 32; }
    else { A = atac_agg; X = x_atac; wb = wat; bias = baf; C = out_a; r0 = (bx - 128) * 32; }
    int w = tid >> 6, lane = tid & 63, n = lane & 15, quad = lane >> 4;

    const f32x4 zf = {0.f, 0.f, 0.f, 0.f};
    f32x4 acc[2][2];
#pragma unroll
    for (int mt = 0; mt < 2; ++mt)
#pragma unroll
        for (int nt = 0; nt < 2; ++nt) acc[mt][nt] = zf;

    for (int k0 = 0; k0 < 384; k0 += 32) {
        __syncthreads();
        {
            int rr = tid >> 3, kq = tid & 7;
            float4 v;
            if (k0 < 128) v = *(const float4*)&A[(size_t)(r0 + rr) * HID + k0 + kq * 4];
            else          v = *(const float4*)&X[(size_t)(r0 + rr) * IN_C + (k0 - 128) + kq * 4];
            ushort4 h, l;
            h.x = f2bf(v.x); h.y = f2bf(v.y); h.z = f2bf(v.z); h.w = f2bf(v.w);
            l.x = f2bf(v.x - bf2f(h.x)); l.y = f2bf(v.y - bf2f(h.y));
            l.z = f2bf(v.z - bf2f(h.z)); l.w = f2bf(v.w - bf2f(h.w));
            *(ushort4*)&ah_s[rr * 40 + kq * 4] = h;
            *(ushort4*)&al_s[rr * 40 + kq * 4] = l;
        }
        __syncthreads();
        bf16x8 Afh[2], Afl[2];
#pragma unroll
        for (int mt = 0; mt < 2; ++mt) {
            Afh[mt] = *(const bf16x8*)&ah_s[(mt * 16 + n) * 40 + quad * 8];
            Afl[mt] = *(const bf16x8*)&al_s[(mt * 16 + n) * 40 + quad * 8];
        }
#pragma unroll
        for (int nt = 0; nt < 2; ++nt) {
            int c = w * 32 + nt * 16 + n;
            size_t o;
            const unsigned short *ph, *pl;
            if (k0 < 128) { o = (size_t)c * 128 + k0 + quad * 8;         ph = wb;         pl = wb + 16384; }
            else          { o = (size_t)c * 256 + (k0 - 128) + quad * 8; ph = wb + 32768; pl = wb + 65536; }
            bf16x8 Bh = *(const bf16x8*)&ph[o];
            bf16x8 Bl = *(const bf16x8*)&pl[o];
#pragma unroll
            for (int mt = 0; mt < 2; ++mt) {
                acc[mt][nt] = mfma16(Afh[mt], Bh, acc[mt][nt]);
                acc[mt][nt] = mfma16(Afh[mt], Bl, acc[mt][nt]);
                acc[mt][nt] = mfma16(Afl[mt], Bh, acc[mt][nt]);
            }
        }
    }
    float bvx[2];
    bvx[0] = bias[w * 32 + n]; bvx[1] = bias[w * 32 + 16 + n];
#pragma unroll
    for (int mt = 0; mt < 2; ++mt)
#pragma unroll
        for (int nt = 0; nt < 2; ++nt)
#pragma unroll
            for (int i = 0; i < 4; ++i) {
                int r = r0 + mt * 16 + quad * 4 + i;
                int c = w * 32 + nt * 16 + n;
                C[(size_t)r * HID + c] = acc[mt][nt][i] + bvx[nt];
            }
}

// ---------------------------------------------------------------- launch
extern "C" void kernel_launch(void* const* d_in, const int* in_sizes, int n_in,
                              void* d_out, int out_size, void* d_ws, size_t ws_size,
                              hipStream_t stream) {
    const float* x_rna = (const float*)d_in[0];
    const float* x_atac = (const float*)d_in[1];
    const float* mask = (const float*)d_in[2];
    const float* Wq = (const float*)d_in[3];  const float* bq = (const float*)d_in[4];
    const float* Wk = (const float*)d_in[5];  const float* bk = (const float*)d_in[6];
    const float* Wvr = (const float*)d_in[7]; const float* bvr = (const float*)d_in[8];
    const float* Wva = (const float*)d_in[9]; const float* bva = (const float*)d_in[10];
    const float* Wor = (const float*)d_in[11]; const float* bor = (const float*)d_in[12];
    const float* Woa = (const float*)d_in[13]; const float* boa = (const float*)d_in[14];
    const float* Wsr = (const float*)d_in[15]; const float* bsr = (const float*)d_in[16];
    const float* Wsa = (const float*)d_in[17]; const float* bsa = (const float*)d_in[18];
    const float* Wdr = (const float*)d_in[19]; const float* bdr = (const float*)d_in[20];
    const float* Wda = (const float*)d_in[21]; const float* bda = (const float*)d_in[22];

    float* out_r = (float*)d_out;
    float* out_a = out_r + N_RNA * HID;

    float* ws = (float*)d_ws;
    unsigned short* qhi = (unsigned short*)ws;            // 2*4096*64 us
    unsigned short* qlo = qhi + 524288;
    unsigned short* khf_hi = qlo + 524288;                // 2*8192*64 us (frag layout)
    unsigned short* khf_lo = khf_hi + 1048576;
    unsigned int* bits2 = (unsigned int*)(ws + 1572864);  // 64*8192*2 uint
    float* v_r = ws + 1572864 + 1048576;                  // 4096x128
    float* v_a = v_r + 524288;                            // 8192x128
    float* Wr1 = v_a + 1048576;                           // (as ushort) wr1h|wr1l
    float* Wr2 = Wr1 + 16384;                             // (as ushort) wr2h|wr2l
    float* brf = Wr2 + 32768;                             // 128 fp32
    float* Wa1 = brf + 128;                               // (as ushort) wa1h|wa1l
    float* Wa2 = Wa1 + 16384;                             // (as ushort) wa2h|wa2l
    float* baf = Wa2 + 32768;                             // 128 fp32
    int* scnt = (int*)(baf + 128);                        // 8192*8 ints
    float* sval = (float*)scnt + 65536;                   // 65536*32
    int* sidx = (int*)(sval + 2097152);                   // 65536*32
    float* rna_agg = (float*)sidx + 2097152;              // 4096x128
    float* atac_agg = rna_agg + 524288;                   // 8192x128
    unsigned short* wt = (unsigned short*)(atac_agg + 1048576);  // 4*128*256*2 us (proj W^T hi/lo)

    unsigned short* wrf = (unsigned short*)Wr1;           // contiguous Wr1|Wr2 region
    unsigned short* waf = (unsigned short*)Wa1;           // contiguous Wa1|Wa2 region

    hipLaunchKernelGGL(wprep, dim3(417), dim3(256), 0, stream,
                       Wq, Wk, Wvr, Wva,
                       Wor, bor, Woa, boa, Wsr, bsr, Wsa, bsa, Wdr, bdr, Wda, bda,
                       wt, wrf, waf, brf, baf);
    hipLaunchKernelGGL(prep_all, dim3(1536), dim3(256), 0, stream,
                       mask, bits2, atac_agg, x_rna, x_atac, wt,
                       bq, bk, bvr, bva,
                       qhi, qlo, khf_hi, khf_lo, v_r, v_a);
    hipLaunchKernelGGL(attn2, dim3(16, 128), dim3(256), 0, stream,
                       qhi, qlo, khf_hi, khf_lo, bits2, scnt, sval, sidx);
    hipLaunchKernelGGL(fin_agg, dim3(2048), dim3(256), 0, stream,
                       scnt, sval, sidx, v_a, v_r, rna_agg, atac_agg);
    hipLaunchKernelGGL(out_gemm, dim3(384), dim3(256), 0, stream,
                       rna_agg, x_rna, wrf, brf,
                       atac_agg, x_atac, waf, baf, out_r, out_a);
}